// Round 1
// baseline (47346.948 us; speedup 1.0000x reference)
//
#include <hip/hip_runtime.h>
#include <stdint.h>

// RTRBM CD-k step, exact JAX-threefry reproduction, fp64 internal math.
// Sizes fixed by the reference: V=1024, H=512, T=128, B=256, CDk=2.
#define NV 1024
#define NH 512
#define TT 128
#define BB 256
#define TBsz (TT*BB)          // 32768
#define HTBsz (NH*TBsz)       // 16777216
#define VTBsz (NV*TBsz)       // 33554432

// ---------------- Threefry-2x32 (JAX exact) ----------------
__host__ __device__ inline void tf2x32(uint32_t k0, uint32_t k1,
                                       uint32_t x0, uint32_t x1,
                                       uint32_t& o0, uint32_t& o1) {
  const uint32_t ks2 = k0 ^ k1 ^ 0x1BD11BDAu;
#define ROTL(x,d) (((x)<<(d))|((x)>>(32-(d))))
#define RND(r) { x0 += x1; x1 = ROTL(x1,r); x1 ^= x0; }
  x0 += k0;  x1 += k1;
  RND(13) RND(15) RND(26) RND(6)
  x0 += k1;  x1 += ks2 + 1u;
  RND(17) RND(29) RND(16) RND(24)
  x0 += ks2; x1 += k0 + 2u;
  RND(13) RND(15) RND(26) RND(6)
  x0 += k0;  x1 += k1 + 3u;
  RND(17) RND(29) RND(16) RND(24)
  x0 += k1;  x1 += ks2 + 4u;
  RND(13) RND(15) RND(26) RND(6)
  x0 += ks2; x1 += k0 + 5u;
  o0 = x0; o1 = x1;
#undef RND
#undef ROTL
}

// JAX partitionable random_bits (32-bit): bits[i] = o0 ^ o1 of TF(key,(hi=0,lo=i));
// uniform = bitcast((bits>>9)|0x3f800000, f32) - 1.0f. Returned as exact double.
__device__ inline double tf_uniform64(uint32_t k0, uint32_t k1, uint32_t i) {
  uint32_t o0, o1;
  tf2x32(k0, k1, 0u, i, o0, o1);
  uint32_t bits = o0 ^ o1;
  uint32_t fb = (bits >> 9) | 0x3f800000u;
  float f = __uint_as_float(fb) - 1.0f;
  return (double)f;
}

__device__ inline double sigmoid64(double x) { return 1.0 / (1.0 + exp(-x)); }

// ---------------- Recurrence: r[:,t,:] (one launch per t, grid=NH, block=BB) ----
__global__ __launch_bounds__(256) void krec(
    const float* __restrict__ vd, const float* __restrict__ W,
    const float* __restrict__ U, const float* __restrict__ bh,
    const float* __restrict__ binit,
    double* __restrict__ r64, float* __restrict__ rout, int t) {
  const int h = blockIdx.x;
  const int b = threadIdx.x;
  const float* __restrict__ vcol = vd + (size_t)t*BB + b;
  const float* __restrict__ Wrow = W + (size_t)h*NV;
  double a0=0, a1=0, a2=0, a3=0;
  for (int v = 0; v < NV; v += 4) {
    a0 += (double)Wrow[v+0] * (double)vcol[(size_t)(v+0)*TBsz];
    a1 += (double)Wrow[v+1] * (double)vcol[(size_t)(v+1)*TBsz];
    a2 += (double)Wrow[v+2] * (double)vcol[(size_t)(v+2)*TBsz];
    a3 += (double)Wrow[v+3] * (double)vcol[(size_t)(v+3)*TBsz];
  }
  double acc = (a0+a1) + (a2+a3);
  if (t == 0) {
    acc += (double)binit[h];
  } else {
    const float* __restrict__ Urow = U + (size_t)h*NH;
    const double* __restrict__ rp = r64 + (size_t)(t-1)*BB + b;
    double u0=0, u1=0, u2=0, u3=0;
    for (int r = 0; r < NH; r += 4) {
      u0 += (double)Urow[r+0] * rp[(size_t)(r+0)*TBsz];
      u1 += (double)Urow[r+1] * rp[(size_t)(r+1)*TBsz];
      u2 += (double)Urow[r+2] * rp[(size_t)(r+2)*TBsz];
      u3 += (double)Urow[r+3] * rp[(size_t)(r+3)*TBsz];
    }
    acc = (acc + ((u0+u1)+(u2+u3))) + (double)bh[h];
  }
  double p = sigmoid64(acc);
  size_t o = (size_t)h*TBsz + (size_t)t*BB + b;
  r64[o] = p;
  rout[o] = (float)p;
}

// ---------------- Elementwise bernoulli from fp64 probabilities ----------------
__global__ __launch_bounds__(256) void ksample(
    const double* __restrict__ p, uint8_t* __restrict__ s,
    uint32_t k0, uint32_t k1, int n) {
  int i = blockIdx.x * 256 + threadIdx.x;
  if (i >= n) return;
  double u = tf_uniform64(k0, k1, (uint32_t)i);
  s[i] = (u < p[i]) ? (uint8_t)1 : (uint8_t)0;
}

// ---------------- v-side: sigmoid(W^T h + b_v) then bernoulli -------------------
__global__ __launch_bounds__(256) void kvis(
    const float* __restrict__ W, const float* __restrict__ bv,
    const uint8_t* __restrict__ hbits, uint8_t* __restrict__ vsamp,
    float* __restrict__ voutf, uint32_t k0, uint32_t k1) {
  const int v = blockIdx.x / TT;
  const int t = blockIdx.x % TT;
  const int b = threadIdx.x;
  const uint8_t* __restrict__ hcol = hbits + (size_t)t*BB + b;
  double a0=0, a1=0, a2=0, a3=0;
  for (int h = 0; h < NH; h += 4) {
    if (hcol[(size_t)(h+0)*TBsz]) a0 += (double)W[(size_t)(h+0)*NV + v];
    if (hcol[(size_t)(h+1)*TBsz]) a1 += (double)W[(size_t)(h+1)*NV + v];
    if (hcol[(size_t)(h+2)*TBsz]) a2 += (double)W[(size_t)(h+2)*NV + v];
    if (hcol[(size_t)(h+3)*TBsz]) a3 += (double)W[(size_t)(h+3)*NV + v];
  }
  double p = sigmoid64(((a0+a1)+(a2+a3)) + (double)bv[v]);
  size_t o = (size_t)v*TBsz + (size_t)t*BB + b;
  double u = tf_uniform64(k0, k1, (uint32_t)o);
  uint8_t smp = (u < p) ? (uint8_t)1 : (uint8_t)0;
  if (vsamp) vsamp[o] = smp;
  if (voutf) voutf[o] = (float)smp;
}

// ---------------- h-side: parallel_r(v1, r_data) then bernoulli -----------------
__global__ __launch_bounds__(256) void khid(
    const float* __restrict__ W, const float* __restrict__ U,
    const float* __restrict__ bh, const float* __restrict__ binit,
    const uint8_t* __restrict__ v1, const double* __restrict__ r64,
    uint8_t* __restrict__ h2, uint32_t k0, uint32_t k1) {
  const int h = blockIdx.x / TT;
  const int t = blockIdx.x % TT;
  const int b = threadIdx.x;
  const uint8_t* __restrict__ vcol = v1 + (size_t)t*BB + b;
  const float* __restrict__ Wrow = W + (size_t)h*NV;
  double a0=0, a1=0, a2=0, a3=0;
  for (int v = 0; v < NV; v += 4) {
    if (vcol[(size_t)(v+0)*TBsz]) a0 += (double)Wrow[v+0];
    if (vcol[(size_t)(v+1)*TBsz]) a1 += (double)Wrow[v+1];
    if (vcol[(size_t)(v+2)*TBsz]) a2 += (double)Wrow[v+2];
    if (vcol[(size_t)(v+3)*TBsz]) a3 += (double)Wrow[v+3];
  }
  double wsum = (a0+a1) + (a2+a3);
  double logit;
  if (t == 0) {
    logit = wsum + (double)binit[h];
  } else {
    const float* __restrict__ Urow = U + (size_t)h*NH;
    const double* __restrict__ rp = r64 + (size_t)(t-1)*BB + b;
    double u0=0, u1=0, u2=0, u3=0;
    for (int r = 0; r < NH; r += 4) {
      u0 += (double)Urow[r+0] * rp[(size_t)(r+0)*TBsz];
      u1 += (double)Urow[r+1] * rp[(size_t)(r+1)*TBsz];
      u2 += (double)Urow[r+2] * rp[(size_t)(r+2)*TBsz];
      u3 += (double)Urow[r+3] * rp[(size_t)(r+3)*TBsz];
    }
    logit = (wsum + ((u0+u1)+(u2+u3))) + (double)bh[h];
  }
  double p = sigmoid64(logit);
  size_t o = (size_t)h*TBsz + (size_t)t*BB + b;
  double u = tf_uniform64(k0, k1, (uint32_t)o);
  h2[o] = (u < p) ? (uint8_t)1 : (uint8_t)0;
}

extern "C" void kernel_launch(void* const* d_in, const int* in_sizes, int n_in,
                              void* d_out, int out_size, void* d_ws, size_t ws_size,
                              hipStream_t stream) {
  const float* vd    = (const float*)d_in[0];
  const float* W     = (const float*)d_in[1];
  const float* U     = (const float*)d_in[2];
  const float* bh    = (const float*)d_in[3];
  const float* binit = (const float*)d_in[4];
  const float* bv    = (const float*)d_in[5];
  // CDk == 2 (concrete per reference); loop structure hardcoded accordingly.

  float* out_v = (float*)d_out;            // (V,T,B) samples, 0/1 f32
  float* out_r = (float*)d_out + VTBsz;    // (H,T,B) r_data f32

  // workspace layout: 134MB f64 r + 16.7MB h1 + 16.7MB h2 + 33.5MB v1 = 201 MB
  double*  r64 = (double*)d_ws;
  uint8_t* h1  = (uint8_t*)(r64 + HTBsz);
  uint8_t* h2  = h1 + HTBsz;
  uint8_t* v1  = h2 + HTBsz;
  (void)ws_size; (void)in_sizes; (void)n_in; (void)out_size;

  // ---- host-side key derivation: jax.random.key(42) = (0,42),
  // partitionable/foldlike split: split(key,n)[i] = TF(key,(0,i)) ----
  uint32_t ka0,ka1, sk0,sk1;
  tf2x32(0u,42u, 0u,0u, ka0,ka1);   // key after 1st split
  tf2x32(0u,42u, 0u,1u, sk0,sk1);   // sk  (h_model #1)
  uint32_t kb0,kb1, k10,k11, k20,k21;
  tf2x32(ka0,ka1, 0u,0u, kb0,kb1);  // key after split(,3)
  tf2x32(ka0,ka1, 0u,1u, k10,k11);  // k1  (v_model #1)
  tf2x32(ka0,ka1, 0u,2u, k20,k21);  // k2  (h_model #2)
  uint32_t kc0,kc1, kf0,kf1;
  tf2x32(kb0,kb1, 0u,0u, kc0,kc1);  // (unused final key)
  tf2x32(kb0,kb1, 0u,1u, kf0,kf1);  // kf  (final v_model)

  // 1) mean-field recurrence r[:,t,:] over T (sequential)
  for (int t = 0; t < TT; ++t)
    krec<<<NH, BB, 0, stream>>>(vd, W, U, bh, binit, r64, out_r, t);

  // 2) h1 = bernoulli(sk, r_data)  (parallel_r(v_data, r_data) == r_data)
  ksample<<<HTBsz/256, 256, 0, stream>>>(r64, h1, sk0, sk1, HTBsz);

  // 3) v1 = bernoulli(k1, sigmoid(W^T h1 + b_v))
  kvis<<<NV*TT, BB, 0, stream>>>(W, bv, h1, v1, nullptr, k10, k11);

  // 4) h2 = bernoulli(k2, parallel_r(v1, r_data))
  khid<<<NH*TT, BB, 0, stream>>>(W, U, bh, binit, v1, r64, h2, k20, k21);

  // 5) v_model = bernoulli(kf, sigmoid(W^T h2 + b_v)) -> output 0
  kvis<<<NV*TT, BB, 0, stream>>>(W, bv, h2, nullptr, out_v, kf0, kf1);
}

// Round 2
// 10362.238 us; speedup vs baseline: 4.5692x; 4.5692x over previous
//
#include <hip/hip_runtime.h>
#include <stdint.h>

typedef unsigned long long u64;

// RTRBM CD-k step, exact JAX-threefry reproduction, fp64 internal math.
#define NV 1024
#define NH 512
#define TT 128
#define BB 256
#define TBsz (TT*BB)          // 32768
#define HTBsz (NH*TBsz)       // 16777216
#define VTBsz (NV*TBsz)       // 33554432
#define NWV (NV/64)           // 16 u64 words per (t,b) for v-sized bits
#define NWH (NH/64)           // 8

// ---------------- Threefry-2x32 (JAX exact) ----------------
__host__ __device__ inline void tf2x32(uint32_t k0, uint32_t k1,
                                       uint32_t x0, uint32_t x1,
                                       uint32_t& o0, uint32_t& o1) {
  const uint32_t ks2 = k0 ^ k1 ^ 0x1BD11BDAu;
#define ROTL(x,d) (((x)<<(d))|((x)>>(32-(d))))
#define RND(r) { x0 += x1; x1 = ROTL(x1,r); x1 ^= x0; }
  x0 += k0;  x1 += k1;
  RND(13) RND(15) RND(26) RND(6)
  x0 += k1;  x1 += ks2 + 1u;
  RND(17) RND(29) RND(16) RND(24)
  x0 += ks2; x1 += k0 + 2u;
  RND(13) RND(15) RND(26) RND(6)
  x0 += k0;  x1 += k1 + 3u;
  RND(17) RND(29) RND(16) RND(24)
  x0 += k1;  x1 += ks2 + 4u;
  RND(13) RND(15) RND(26) RND(6)
  x0 += ks2; x1 += k0 + 5u;
  o0 = x0; o1 = x1;
#undef RND
#undef ROTL
}

__device__ inline double tf_uniform64(uint32_t k0, uint32_t k1, uint32_t i) {
  uint32_t o0, o1;
  tf2x32(k0, k1, 0u, i, o0, o1);
  uint32_t bits = o0 ^ o1;
  uint32_t fb = (bits >> 9) | 0x3f800000u;
  float f = __uint_as_float(fb) - 1.0f;
  return (double)f;
}

__device__ inline double sigmoid64(double x) { return 1.0 / (1.0 + exp(-x)); }

// ---------------- f32 -> f64 convert ----------------
__global__ __launch_bounds__(256) void kcvt(const float* __restrict__ s,
                                            double* __restrict__ d, int n) {
  int i = blockIdx.x * 256 + threadIdx.x;
  if (i < n) d[i] = (double)s[i];
}

// ---------------- bit-pack: u8 [NR][TBsz] -> u64 [TBsz][NR/64] ----------------
__global__ __launch_bounds__(256) void kpack_u8(const uint8_t* __restrict__ in,
                                                u64* __restrict__ out, int nw) {
  int tb = blockIdx.x * 256 + threadIdx.x;
  for (int w = 0; w < nw; ++w) {
    u64 m = 0;
    #pragma unroll 8
    for (int j = 0; j < 64; ++j)
      m |= (u64)(in[(size_t)(w*64 + j)*TBsz + tb]) << j;
    out[(size_t)tb*nw + w] = m;
  }
}

// same but f32 0/1 input (v_data)
__global__ __launch_bounds__(256) void kpack_f32(const float* __restrict__ in,
                                                 u64* __restrict__ out, int nw) {
  int tb = blockIdx.x * 256 + threadIdx.x;
  for (int w = 0; w < nw; ++w) {
    u64 m = 0;
    #pragma unroll 8
    for (int j = 0; j < 64; ++j)
      m |= (u64)(in[(size_t)(w*64 + j)*TBsz + tb] != 0.0f ? 1 : 0) << j;
    out[(size_t)tb*nw + w] = m;
  }
}

// ---------------- Wv64[h][t][b] = sum_v W[h,v]*vbit  (t-parallel) ----------------
// grid: TT * (NH/8), t-major. 256 threads = b.
__global__ __launch_bounds__(256) void kWv(const u64* __restrict__ vb,
                                           const double* __restrict__ W64,
                                           double* __restrict__ Wv64) {
  const int HM = 8;
  int t  = blockIdx.x / (NH/HM);
  int h0 = (blockIdx.x % (NH/HM)) * HM;
  int tb = t*BB + threadIdx.x;
  u64 m[NWV];
  #pragma unroll
  for (int w = 0; w < NWV; ++w) m[w] = vb[(size_t)tb*NWV + w];
  double acc[HM];
  #pragma unroll
  for (int i = 0; i < HM; ++i) acc[i] = 0.0;
  for (int w = 0; w < NWV; ++w) {
    u64 mw = m[w];
    #pragma unroll 8
    for (int j = 0; j < 64; ++j) {
      double bd = (double)((unsigned)((mw >> j) & 1ull));
      int v = w*64 + j;
      #pragma unroll
      for (int i = 0; i < HM; ++i)
        acc[i] = fma(bd, W64[(size_t)(h0+i)*NV + v], acc[i]);
    }
  }
  #pragma unroll
  for (int i = 0; i < HM; ++i)
    Wv64[(size_t)(h0+i)*TBsz + tb] = acc[i];
}

// ---------------- sequential step: r[t] = sigmoid(Wv + U@r[t-1] + bias) -----------
// grid: 256 blocks * 128 threads; 4 h per thread.
__global__ __launch_bounds__(128) void kstep(const double* __restrict__ Wv64,
                                             const double* __restrict__ U64,
                                             const float* __restrict__ bh,
                                             const float* __restrict__ binit,
                                             double* __restrict__ r64,
                                             float* __restrict__ rout, int t) {
  const int HM = 4;
  int h0 = (blockIdx.x >> 1) * HM;
  int b  = ((blockIdx.x & 1) << 7) + threadIdx.x;
  int tb = t*BB + b;
  double acc[HM];
  #pragma unroll
  for (int i = 0; i < HM; ++i) acc[i] = Wv64[(size_t)(h0+i)*TBsz + tb];
  if (t > 0) {
    const double* __restrict__ rp = r64 + (size_t)(t-1)*BB + b;
    #pragma unroll 4
    for (int r = 0; r < NH; ++r) {
      double rv = rp[(size_t)r*TBsz];
      #pragma unroll
      for (int i = 0; i < HM; ++i)
        acc[i] = fma(U64[(size_t)(h0+i)*NH + r], rv, acc[i]);
    }
    #pragma unroll
    for (int i = 0; i < HM; ++i) acc[i] += (double)bh[h0+i];
  } else {
    #pragma unroll
    for (int i = 0; i < HM; ++i) acc[i] += (double)binit[h0+i];
  }
  #pragma unroll
  for (int i = 0; i < HM; ++i) {
    double p = sigmoid64(acc[i]);
    size_t o = (size_t)(h0+i)*TBsz + tb;
    r64[o] = p;
    rout[o] = (float)p;
  }
}

// ---------------- elementwise bernoulli from fp64 probabilities ----------------
__global__ __launch_bounds__(256) void ksample(const double* __restrict__ p,
                                               uint8_t* __restrict__ s,
                                               uint32_t k0, uint32_t k1, int n) {
  int i = blockIdx.x * 256 + threadIdx.x;
  if (i >= n) return;
  double u = tf_uniform64(k0, k1, (uint32_t)i);
  s[i] = (u < p[i]) ? (uint8_t)1 : (uint8_t)0;
}

// ---------------- v-side: sigmoid(W^T h + b_v), bernoulli ----------------------
// grid: TT * (NV/8), t-major. 8 v per thread.
__global__ __launch_bounds__(256) void kvis(const double* __restrict__ W64,
                                            const float* __restrict__ bv,
                                            const u64* __restrict__ hbits,
                                            uint8_t* __restrict__ vs,
                                            float* __restrict__ vf,
                                            uint32_t k0, uint32_t k1) {
  const int VM = 8;
  int t  = blockIdx.x / (NV/VM);
  int v0 = (blockIdx.x % (NV/VM)) * VM;
  int tb = t*BB + threadIdx.x;
  u64 hb[NWH];
  #pragma unroll
  for (int w = 0; w < NWH; ++w) hb[w] = hbits[(size_t)tb*NWH + w];
  double acc[VM];
  #pragma unroll
  for (int i = 0; i < VM; ++i) acc[i] = 0.0;
  for (int w = 0; w < NWH; ++w) {
    u64 mw = hb[w];
    #pragma unroll 8
    for (int j = 0; j < 64; ++j) {
      double bd = (double)((unsigned)((mw >> j) & 1ull));
      int h = w*64 + j;
      #pragma unroll
      for (int i = 0; i < VM; ++i)
        acc[i] = fma(bd, W64[(size_t)h*NV + v0 + i], acc[i]);
    }
  }
  #pragma unroll
  for (int i = 0; i < VM; ++i) {
    double p = sigmoid64(acc[i] + (double)bv[v0+i]);
    size_t o = (size_t)(v0+i)*TBsz + tb;
    double u = tf_uniform64(k0, k1, (uint32_t)o);
    uint8_t smp = (u < p) ? (uint8_t)1 : (uint8_t)0;
    if (vs) vs[o] = smp;
    if (vf) vf[o] = smp ? 1.0f : 0.0f;
  }
}

// ---------------- h-side: sigmoid(W v1 + U r_lag + bias), bernoulli -------------
// grid: TT * (NH/8), t-major. 8 h per thread.
__global__ __launch_bounds__(256) void khid(const u64* __restrict__ vbits,
                                            const double* __restrict__ W64,
                                            const double* __restrict__ U64,
                                            const float* __restrict__ bh,
                                            const float* __restrict__ binit,
                                            const double* __restrict__ r64,
                                            uint8_t* __restrict__ hs,
                                            uint32_t k0, uint32_t k1) {
  const int HM = 8;
  int t  = blockIdx.x / (NH/HM);
  int h0 = (blockIdx.x % (NH/HM)) * HM;
  int tb = t*BB + threadIdx.x;
  u64 m[NWV];
  #pragma unroll
  for (int w = 0; w < NWV; ++w) m[w] = vbits[(size_t)tb*NWV + w];
  double acc[HM];
  #pragma unroll
  for (int i = 0; i < HM; ++i) acc[i] = 0.0;
  for (int w = 0; w < NWV; ++w) {
    u64 mw = m[w];
    #pragma unroll 8
    for (int j = 0; j < 64; ++j) {
      double bd = (double)((unsigned)((mw >> j) & 1ull));
      int v = w*64 + j;
      #pragma unroll
      for (int i = 0; i < HM; ++i)
        acc[i] = fma(bd, W64[(size_t)(h0+i)*NV + v], acc[i]);
    }
  }
  if (t > 0) {
    const double* __restrict__ rp = r64 + (size_t)(t-1)*BB + threadIdx.x;
    #pragma unroll 4
    for (int r = 0; r < NH; ++r) {
      double rv = rp[(size_t)r*TBsz];
      #pragma unroll
      for (int i = 0; i < HM; ++i)
        acc[i] = fma(U64[(size_t)(h0+i)*NH + r], rv, acc[i]);
    }
    #pragma unroll
    for (int i = 0; i < HM; ++i) acc[i] += (double)bh[h0+i];
  } else {
    #pragma unroll
    for (int i = 0; i < HM; ++i) acc[i] += (double)binit[h0+i];
  }
  #pragma unroll
  for (int i = 0; i < HM; ++i) {
    double p = sigmoid64(acc[i]);
    size_t o = (size_t)(h0+i)*TBsz + tb;
    double u = tf_uniform64(k0, k1, (uint32_t)o);
    hs[o] = (u < p) ? (uint8_t)1 : (uint8_t)0;
  }
}

extern "C" void kernel_launch(void* const* d_in, const int* in_sizes, int n_in,
                              void* d_out, int out_size, void* d_ws, size_t ws_size,
                              hipStream_t stream) {
  const float* vd    = (const float*)d_in[0];
  const float* W     = (const float*)d_in[1];
  const float* U     = (const float*)d_in[2];
  const float* bh    = (const float*)d_in[3];
  const float* binit = (const float*)d_in[4];
  const float* bv    = (const float*)d_in[5];

  float* out_v = (float*)d_out;            // (V,T,B) samples, 0/1 f32 (written last)
  float* out_r = (float*)d_out + VTBsz;    // (H,T,B) r_data f32

  // ws layout (186.6 MB; known-available >= 201.3 MB)
  char* w = (char*)d_ws;
  double*  r64    = (double*)w;                 w += (size_t)HTBsz*8;    // 134.2 MB
  uint8_t* u8s    = (uint8_t*)w;                w += (size_t)VTBsz;      // 33.5 MB (h1u8/v1u8/h2u8, sequential lifetimes)
  u64*     vdbits = (u64*)w;                    w += (size_t)TBsz*NWV*8; // 4 MB
  u64*     v1bits = (u64*)w;                    w += (size_t)TBsz*NWV*8; // 4 MB
  u64*     h1bits = (u64*)w;                    w += (size_t)TBsz*NWH*8; // 2 MB
  u64*     h2bits = (u64*)w;                    w += (size_t)TBsz*NWH*8; // 2 MB
  double*  W64    = (double*)w;                 w += (size_t)NH*NV*8;    // 4 MB
  double*  U64    = (double*)w;                 w += (size_t)NH*NH*8;    // 2 MB
  // Wv64 lives in the out_v region (134.2 MB), dead until final kvis.
  double*  Wv64   = (double*)d_out;
  (void)ws_size; (void)in_sizes; (void)n_in; (void)out_size;

  // host-side key derivation (jax.random.key(42), partitionable threefry splits)
  uint32_t ka0,ka1, sk0,sk1;
  tf2x32(0u,42u, 0u,0u, ka0,ka1);
  tf2x32(0u,42u, 0u,1u, sk0,sk1);
  uint32_t kb0,kb1, k10,k11, k20,k21;
  tf2x32(ka0,ka1, 0u,0u, kb0,kb1);
  tf2x32(ka0,ka1, 0u,1u, k10,k11);
  tf2x32(ka0,ka1, 0u,2u, k20,k21);
  uint32_t kc0,kc1, kf0,kf1;
  tf2x32(kb0,kb1, 0u,0u, kc0,kc1);
  tf2x32(kb0,kb1, 0u,1u, kf0,kf1);

  // 0) f64 copies of W, U; bit-pack v_data
  kcvt<<<(NH*NV+255)/256, 256, 0, stream>>>(W, W64, NH*NV);
  kcvt<<<(NH*NH+255)/256, 256, 0, stream>>>(U, U64, NH*NH);
  kpack_f32<<<TBsz/256, 256, 0, stream>>>(vd, vdbits, NWV);

  // 1) Wv64 = W @ v_data (all t in parallel)
  kWv<<<TT*(NH/8), 256, 0, stream>>>(vdbits, W64, Wv64);

  // 2) sequential mean-field recurrence over t
  for (int t = 0; t < TT; ++t)
    kstep<<<256, 128, 0, stream>>>(Wv64, U64, bh, binit, r64, out_r, t);

  // 3) h1 = bernoulli(sk, r_data); pack
  ksample<<<HTBsz/256, 256, 0, stream>>>(r64, u8s, sk0, sk1, HTBsz);
  kpack_u8<<<TBsz/256, 256, 0, stream>>>(u8s, h1bits, NWH);

  // 4) v1 = bernoulli(k1, sigmoid(W^T h1 + b_v)); pack
  kvis<<<TT*(NV/8), 256, 0, stream>>>(W64, bv, h1bits, u8s, nullptr, k10, k11);
  kpack_u8<<<TBsz/256, 256, 0, stream>>>(u8s, v1bits, NWV);

  // 5) h2 = bernoulli(k2, sigmoid(W v1 + U r_lag + bias)); pack
  khid<<<TT*(NH/8), 256, 0, stream>>>(v1bits, W64, U64, bh, binit, r64, u8s, k20, k21);
  kpack_u8<<<TBsz/256, 256, 0, stream>>>(u8s, h2bits, NWH);

  // 6) v_model = bernoulli(kf, sigmoid(W^T h2 + b_v)) -> out_v (overwrites Wv64 scratch)
  kvis<<<TT*(NV/8), 256, 0, stream>>>(W64, bv, h2bits, nullptr, out_v, kf0, kf1);
}